// Round 1
// baseline (270.022 us; speedup 1.0000x reference)
//
#include <hip/hip_runtime.h>

#define C_DIM 1280
#define K_DIM 1280      // GEMM K = C
#define N_DIM 2560      // GEMM N = 2C
#define HWSZ 16
#define CHW (C_DIM*HWSZ)

typedef __bf16 bf16;
typedef __attribute__((ext_vector_type(8))) __bf16 bf16x8;
typedef __attribute__((ext_vector_type(4))) float f32x4;
typedef __attribute__((ext_vector_type(2))) float f32x2;

__device__ __forceinline__ void gload_lds16(const void* g, void* l) {
  __builtin_amdgcn_global_load_lds(
      (const __attribute__((address_space(1))) void*)g,
      (__attribute__((address_space(3))) void*)l, 16, 0, 0);
}

// ---------------- h = relu(pose @ W1 + b1), store bf16 ----------------
__global__ __launch_bounds__(256) void pose_mlp1(
    const float* __restrict__ pose, const float* __restrict__ W1,
    const float* __restrict__ b1, bf16* __restrict__ h)
{
  int idx = blockIdx.x * 256 + threadIdx.x;   // E*C threads, exact
  int e = idx / C_DIM;
  int c = idx - e * C_DIM;
  const float* p = pose + e * 9;
  float s = b1[c];
  #pragma unroll
  for (int k = 0; k < 9; k++) s += p[k] * W1[k * C_DIM + c];
  s = s > 0.f ? s : 0.f;
  h[idx] = (bf16)s;
}

// ---------------- W2 (1280 x 2560) -> W2t (2560 x 1280) bf16 ----------------
__global__ __launch_bounds__(256) void transpose_w2(
    const float* __restrict__ W2, bf16* __restrict__ W2t)
{
  __shared__ float tile[32][33];
  int n0 = blockIdx.x * 32;    // 2560/32 = 80
  int k0 = blockIdx.y * 32;    // 1280/32 = 40
  int tx = threadIdx.x;        // 32
  int ty = threadIdx.y;        // 8
  #pragma unroll
  for (int i = 0; i < 32; i += 8)
    tile[ty + i][tx] = W2[(size_t)(k0 + ty + i) * N_DIM + n0 + tx];
  __syncthreads();
  #pragma unroll
  for (int i = 0; i < 32; i += 8)
    W2t[(size_t)(n0 + ty + i) * K_DIM + k0 + tx] = (bf16)tile[tx][ty + i];
}

// ---------------- CSR build ----------------
__global__ void zero_cnt(int* cnt, int N) {
  int i = blockIdx.x * 256 + threadIdx.x;
  if (i < N) cnt[i] = 0;
}
__global__ void count_dst(const int* __restrict__ dst, int* cnt, int E) {
  int e = blockIdx.x * 256 + threadIdx.x;
  if (e < E) atomicAdd(&cnt[dst[e]], 1);
}
__global__ __launch_bounds__(1024) void scan_offsets(
    const int* __restrict__ cnt, int* offsets, int* cursor, int N, int E)
{
  __shared__ int buf[1024];
  int t = threadIdx.x;
  int v = (t < N) ? cnt[t] : 0;
  buf[t] = v;
  __syncthreads();
  #pragma unroll
  for (int off = 1; off < 1024; off <<= 1) {
    int x = (t >= off) ? buf[t - off] : 0;
    __syncthreads();
    buf[t] += x;
    __syncthreads();
  }
  if (t < N) {
    int incl = buf[t];
    int excl = incl - v;
    offsets[t] = excl;
    cursor[t] = excl;
    if (t == N - 1) offsets[N] = incl;
  }
}
__global__ void fill_eids(const int* __restrict__ dst, int* cursor,
                          int* eids, int E) {
  int e = blockIdx.x * 256 + threadIdx.x;
  if (e < E) {
    int p = atomicAdd(&cursor[dst[e]], 1);
    eids[p] = e;
  }
}

// ---------------- GEMM: Eout = sigmoid(h @ W2 + b2), fp32 out ----------------
// A: E x 1280 bf16 (row-major, K-contig); Bt: 2560 x 1280 bf16 (N x K)
__global__ __launch_bounds__(256) void gemm_sigmoid(
    const bf16* __restrict__ A, const bf16* __restrict__ Bt,
    const float* __restrict__ b2, float* __restrict__ Eo)
{
  __shared__ __align__(16) bf16 As[128 * 64];
  __shared__ __align__(16) bf16 Bs[128 * 64];
  const int tid = threadIdx.x;
  const int lane = tid & 63;
  const int wave = tid >> 6;      // 4 waves, 2x2
  const int wm = wave >> 1, wn = wave & 1;
  const long bm = (long)blockIdx.x * 128;
  const long bn = (long)blockIdx.y * 128;

  const int srow = lane >> 3;           // row within 8-row chunk
  const int skc = (lane & 7) * 8;       // bf16 k offset within 64

  f32x4 acc[4][4];
  #pragma unroll
  for (int i = 0; i < 4; i++)
    #pragma unroll
    for (int j = 0; j < 4; j++) acc[i][j] = f32x4{0.f, 0.f, 0.f, 0.f};

  const bf16* Ag = A + bm * K_DIM;
  const bf16* Bg = Bt + bn * K_DIM;
  const int fr = lane & 15;
  const int fk = (lane >> 4) * 8;

  for (int k0 = 0; k0 < K_DIM; k0 += 64) {
    __syncthreads();
    #pragma unroll
    for (int i = 0; i < 4; i++) {
      const int ch = wave * 4 + i;          // 16 chunks of 1KB each
      const int row = ch * 8 + srow;
      gload_lds16(Ag + (long)row * K_DIM + k0 + skc, As + ch * 512);
      gload_lds16(Bg + (long)row * K_DIM + k0 + skc, Bs + ch * 512);
    }
    __syncthreads();
    #pragma unroll
    for (int kk = 0; kk < 64; kk += 32) {
      bf16x8 a[4], b[4];
      #pragma unroll
      for (int m = 0; m < 4; m++)
        a[m] = *(const bf16x8*)(As + (wm * 64 + m * 16 + fr) * 64 + kk + fk);
      #pragma unroll
      for (int n = 0; n < 4; n++)
        b[n] = *(const bf16x8*)(Bs + (wn * 64 + n * 16 + fr) * 64 + kk + fk);
      #pragma unroll
      for (int m = 0; m < 4; m++)
        #pragma unroll
        for (int n = 0; n < 4; n++)
          acc[m][n] = __builtin_amdgcn_mfma_f32_16x16x32_bf16(
              a[m], b[n], acc[m][n], 0, 0, 0);
    }
  }

  // epilogue: sigmoid(acc + b2), write fp32
  const int r0 = (lane >> 4) * 4;
  #pragma unroll
  for (int n = 0; n < 4; n++) {
    const long col = bn + wn * 64 + n * 16 + fr;
    const float bias = b2[col];
    #pragma unroll
    for (int m = 0; m < 4; m++) {
      const long rowb = bm + wm * 64 + m * 16 + r0;
      #pragma unroll
      for (int r = 0; r < 4; r++) {
        float v = acc[m][n][r] + bias;
        Eo[(rowb + r) * N_DIM + col] = 1.f / (1.f + __expf(-v));
      }
    }
  }
}

// ---------------- scatter-mean: out[n] = mean_e(gamma*image[src]+beta) ----------------
// grid (N, 4); block 256. Chunk = 320 channels. Thread: q=t&3 (hw quad), cl=t>>2.
__global__ __launch_bounds__(256) void scatter_mean(
    const float* __restrict__ Eo,     // E x 2560, (gamma,beta) interleaved
    const float* __restrict__ image,  // N x C x 16
    const int* __restrict__ src,
    const int* __restrict__ offsets,  // N+1
    const int* __restrict__ eids,     // E
    float* __restrict__ out)          // N x C x 16
{
  const int n = blockIdx.x;
  const int c0 = blockIdx.y * 320;
  const int t = threadIdx.x;
  const int q = t & 3;
  const int cl = t >> 2;

  const int beg = offsets[n], end = offsets[n + 1];
  f32x4 acc[5];
  #pragma unroll
  for (int k = 0; k < 5; k++) acc[k] = f32x4{0.f, 0.f, 0.f, 0.f};

  for (int ei = beg; ei < end; ++ei) {
    const int e = eids[ei];
    const int s = src[e];
    const float* imgb = image + (size_t)s * CHW;
    const float* gb = Eo + (size_t)e * N_DIM;
    #pragma unroll
    for (int k = 0; k < 5; k++) {
      const int c = c0 + cl + 64 * k;
      f32x2 gbp = *(const f32x2*)(gb + 2 * c);
      f32x4 img = *(const f32x4*)(imgb + c * HWSZ + q * 4);
      acc[k] += gbp.x * img + gbp.y;
    }
  }
  const int cnt = end - beg;
  const float inv = cnt > 0 ? 1.f / (float)cnt : 0.f;
  float* ob = out + (size_t)n * CHW;
  #pragma unroll
  for (int k = 0; k < 5; k++) {
    const int c = c0 + cl + 64 * k;
    *(f32x4*)(ob + c * HWSZ + q * 4) = acc[k] * inv;
  }
}

// ---------------- launch ----------------
extern "C" void kernel_launch(void* const* d_in, const int* in_sizes, int n_in,
                              void* d_out, int out_size, void* d_ws, size_t ws_size,
                              hipStream_t stream) {
  const float* pose  = (const float*)d_in[0];
  const float* image = (const float*)d_in[1];
  const float* W1    = (const float*)d_in[2];
  const float* b1    = (const float*)d_in[3];
  const float* W2    = (const float*)d_in[4];
  const float* b2    = (const float*)d_in[5];
  const int*   src   = (const int*)d_in[6];
  const int*   dst   = (const int*)d_in[7];
  const int E = in_sizes[6];                     // 8192
  const int N = in_sizes[1] / CHW;               // 1024
  float* out = (float*)d_out;

  char* ws = (char*)d_ws;
  size_t off = 0;
  auto alloc = [&](size_t bytes) {
    void* p = ws + off;
    off = (off + bytes + 255) & ~(size_t)255;
    return p;
  };
  bf16* h     = (bf16*)alloc((size_t)E * C_DIM * sizeof(bf16));
  bf16* W2t   = (bf16*)alloc((size_t)N_DIM * K_DIM * sizeof(bf16));
  float* Eout = (float*)alloc((size_t)E * N_DIM * sizeof(float));
  int* cnt    = (int*)alloc((size_t)N * sizeof(int));
  int* offs   = (int*)alloc((size_t)(N + 1) * sizeof(int));
  int* cursor = (int*)alloc((size_t)N * sizeof(int));
  int* eids   = (int*)alloc((size_t)E * sizeof(int));

  // CSR build
  zero_cnt<<<(N + 255) / 256, 256, 0, stream>>>(cnt, N);
  count_dst<<<(E + 255) / 256, 256, 0, stream>>>(dst, cnt, E);
  scan_offsets<<<1, 1024, 0, stream>>>(cnt, offs, cursor, N, E);
  fill_eids<<<(E + 255) / 256, 256, 0, stream>>>(dst, cursor, eids, E);

  // MLP layer 1 + weight transpose
  pose_mlp1<<<(E * C_DIM) / 256, 256, 0, stream>>>(pose, W1, b1, h);
  transpose_w2<<<dim3(N_DIM / 32, K_DIM / 32), dim3(32, 8), 0, stream>>>(W2, W2t);

  // MLP layer 2 (bf16 MFMA) + sigmoid
  gemm_sigmoid<<<dim3(E / 128, N_DIM / 128), 256, 0, stream>>>(h, W2t, b2, Eout);

  // FiLM + segment mean
  scatter_mean<<<dim3(N, 4), 256, 0, stream>>>(Eout, image, src, offs, eids, out);
}

// Round 2
// 243.661 us; speedup vs baseline: 1.1082x; 1.1082x over previous
//
#include <hip/hip_runtime.h>

#define C_DIM 1280
#define K_DIM 1280      // GEMM K = C
#define N_DIM 2560      // GEMM N = 2C
#define HWSZ 16
#define CHW (C_DIM*HWSZ)

typedef __bf16 bf16;
typedef __attribute__((ext_vector_type(8))) __bf16 bf16x8;
typedef __attribute__((ext_vector_type(4))) float f32x4;

__device__ __forceinline__ void gload_lds16(const void* g, void* l) {
  __builtin_amdgcn_global_load_lds(
      (const __attribute__((address_space(1))) void*)g,
      (__attribute__((address_space(3))) void*)l, 16, 0, 0);
}

// ---------------- h = relu(pose @ W1 + b1), store bf16 ----------------
__global__ __launch_bounds__(256) void pose_mlp1(
    const float* __restrict__ pose, const float* __restrict__ W1,
    const float* __restrict__ b1, bf16* __restrict__ h)
{
  int idx = blockIdx.x * 256 + threadIdx.x;   // E*C threads, exact
  int e = idx / C_DIM;
  int c = idx - e * C_DIM;
  const float* p = pose + e * 9;
  float s = b1[c];
  #pragma unroll
  for (int k = 0; k < 9; k++) s += p[k] * W1[k * C_DIM + c];
  s = s > 0.f ? s : 0.f;
  h[idx] = (bf16)s;
}

// ---------------- W2 (1280 x 2560) -> W2t (2560 x 1280) bf16 ----------------
__global__ __launch_bounds__(256) void transpose_w2(
    const float* __restrict__ W2, bf16* __restrict__ W2t)
{
  __shared__ float tile[32][33];
  int n0 = blockIdx.x * 32;    // 2560/32 = 80
  int k0 = blockIdx.y * 32;    // 1280/32 = 40
  int tx = threadIdx.x;        // 32
  int ty = threadIdx.y;        // 8
  #pragma unroll
  for (int i = 0; i < 32; i += 8)
    tile[ty + i][tx] = W2[(size_t)(k0 + ty + i) * N_DIM + n0 + tx];
  __syncthreads();
  #pragma unroll
  for (int i = 0; i < 32; i += 8)
    W2t[(size_t)(n0 + ty + i) * K_DIM + k0 + tx] = (bf16)tile[tx][ty + i];
}

// ---------------- CSR build: one block, LDS counts/scan/cursor ----------------
// pairs[p] = (edge id, src[e]) in CSR order over dst.
__global__ __launch_bounds__(1024) void build_csr(
    const int* __restrict__ dst, const int* __restrict__ src,
    int* __restrict__ offsets, int2* __restrict__ pairs, int E, int N)
{
  __shared__ int buf[1024];
  __shared__ int cur[1024];
  const int t = threadIdx.x;
  buf[t] = 0;
  __syncthreads();
  for (int e = t; e < E; e += 1024) atomicAdd(&buf[dst[e]], 1);
  __syncthreads();
  const int v = buf[t];
  #pragma unroll
  for (int off = 1; off < 1024; off <<= 1) {
    int x = (t >= off) ? buf[t - off] : 0;
    __syncthreads();
    buf[t] += x;
    __syncthreads();
  }
  const int excl = buf[t] - v;
  cur[t] = excl;
  if (t < N) offsets[t] = excl;
  if (t == 0) offsets[N] = E;
  __syncthreads();
  for (int e = t; e < E; e += 1024) {
    const int d = dst[e];
    const int p = atomicAdd(&cur[d], 1);
    pairs[p] = make_int2(e, src[e]);
  }
}

// ---------------- GEMM: Eout = sigmoid(h @ W2 + b2), bf16 out ----------------
// A: E x 1280 bf16 (row-major, K-contig); Bt: 2560 x 1280 bf16 (N x K)
__global__ __launch_bounds__(256) void gemm_sigmoid(
    const bf16* __restrict__ A, const bf16* __restrict__ Bt,
    const float* __restrict__ b2, bf16* __restrict__ Eo)
{
  __shared__ __align__(16) bf16 As[128 * 64];
  __shared__ __align__(16) bf16 Bs[128 * 64];
  const int tid = threadIdx.x;
  const int lane = tid & 63;
  const int wave = tid >> 6;      // 4 waves, 2x2
  const int wm = wave >> 1, wn = wave & 1;
  const long bm = (long)blockIdx.x * 128;
  const long bn = (long)blockIdx.y * 128;

  const int srow = lane >> 3;           // row within 8-row chunk
  const int skc = (lane & 7) * 8;       // bf16 k offset within 64

  f32x4 acc[4][4];
  #pragma unroll
  for (int i = 0; i < 4; i++)
    #pragma unroll
    for (int j = 0; j < 4; j++) acc[i][j] = f32x4{0.f, 0.f, 0.f, 0.f};

  const bf16* Ag = A + bm * K_DIM;
  const bf16* Bg = Bt + bn * K_DIM;
  const int fr = lane & 15;
  const int fk = (lane >> 4) * 8;

  for (int k0 = 0; k0 < K_DIM; k0 += 64) {
    __syncthreads();
    #pragma unroll
    for (int i = 0; i < 4; i++) {
      const int ch = wave * 4 + i;          // 16 chunks of 1KB each
      const int row = ch * 8 + srow;
      gload_lds16(Ag + (long)row * K_DIM + k0 + skc, As + ch * 512);
      gload_lds16(Bg + (long)row * K_DIM + k0 + skc, Bs + ch * 512);
    }
    __syncthreads();
    #pragma unroll
    for (int kk = 0; kk < 64; kk += 32) {
      bf16x8 a[4], b[4];
      #pragma unroll
      for (int m = 0; m < 4; m++)
        a[m] = *(const bf16x8*)(As + (wm * 64 + m * 16 + fr) * 64 + kk + fk);
      #pragma unroll
      for (int n = 0; n < 4; n++)
        b[n] = *(const bf16x8*)(Bs + (wn * 64 + n * 16 + fr) * 64 + kk + fk);
      #pragma unroll
      for (int m = 0; m < 4; m++)
        #pragma unroll
        for (int n = 0; n < 4; n++)
          acc[m][n] = __builtin_amdgcn_mfma_f32_16x16x32_bf16(
              a[m], b[n], acc[m][n], 0, 0, 0);
    }
  }

  // epilogue: sigmoid(acc + b2), write bf16
  const int r0 = (lane >> 4) * 4;
  #pragma unroll
  for (int n = 0; n < 4; n++) {
    const long col = bn + wn * 64 + n * 16 + fr;
    const float bias = b2[col];
    #pragma unroll
    for (int m = 0; m < 4; m++) {
      const long rowb = bm + wm * 64 + m * 16 + r0;
      #pragma unroll
      for (int r = 0; r < 4; r++) {
        float v = acc[m][n][r] + bias;
        Eo[(rowb + r) * N_DIM + col] = (bf16)(1.f / (1.f + __expf(-v)));
      }
    }
  }
}

// ---------------- scatter-mean: out[n] = mean_e(gamma*image[src]+beta) ----------------
// grid (N, 10); block 256. Chunk = 128 channels. Thread: q=t&3 (hw quad), cl=t>>2.
__global__ __launch_bounds__(256) void scatter_mean(
    const ushort* __restrict__ Eo,    // E x 2560 bf16, (gamma,beta) interleaved
    const float* __restrict__ image,  // N x C x 16
    const int2* __restrict__ pairs,   // (eid, src) in CSR order
    const int* __restrict__ offsets,  // N+1
    float* __restrict__ out)          // N x C x 16
{
  const int n = blockIdx.x;
  const int c0 = blockIdx.y * 128;
  const int t = threadIdx.x;
  const int q = t & 3;
  const int cl = t >> 2;
  const int ca = c0 + cl;
  const int cb = ca + 64;

  const int beg = offsets[n], end = offsets[n + 1];
  f32x4 acc0 = {0.f, 0.f, 0.f, 0.f};
  f32x4 acc1 = {0.f, 0.f, 0.f, 0.f};

  int2 pr;
  if (beg < end) pr = pairs[beg];
  for (int ei = beg; ei < end; ++ei) {
    const int2 cp = pr;
    if (ei + 1 < end) pr = pairs[ei + 1];
    const float* imgb = image + (size_t)cp.y * CHW;
    const ushort* gbp = Eo + (size_t)cp.x * N_DIM;
    const uint u0 = *(const uint*)(gbp + 2 * ca);   // lo=gamma, hi=beta
    const uint u1 = *(const uint*)(gbp + 2 * cb);
    const f32x4 i0 = *(const f32x4*)(imgb + ca * HWSZ + q * 4);
    const f32x4 i1 = *(const f32x4*)(imgb + cb * HWSZ + q * 4);
    const float g0 = __uint_as_float(u0 << 16);
    const float be0 = __uint_as_float(u0 & 0xffff0000u);
    const float g1 = __uint_as_float(u1 << 16);
    const float be1 = __uint_as_float(u1 & 0xffff0000u);
    acc0 += g0 * i0 + be0;
    acc1 += g1 * i1 + be1;
  }
  const int cnt = end - beg;
  const float inv = cnt > 0 ? 1.f / (float)cnt : 0.f;
  float* ob = out + (size_t)n * CHW;
  __builtin_nontemporal_store(acc0 * inv, (f32x4*)(ob + ca * HWSZ + q * 4));
  __builtin_nontemporal_store(acc1 * inv, (f32x4*)(ob + cb * HWSZ + q * 4));
}

// ---------------- launch ----------------
extern "C" void kernel_launch(void* const* d_in, const int* in_sizes, int n_in,
                              void* d_out, int out_size, void* d_ws, size_t ws_size,
                              hipStream_t stream) {
  const float* pose  = (const float*)d_in[0];
  const float* image = (const float*)d_in[1];
  const float* W1    = (const float*)d_in[2];
  const float* b1    = (const float*)d_in[3];
  const float* W2    = (const float*)d_in[4];
  const float* b2    = (const float*)d_in[5];
  const int*   src   = (const int*)d_in[6];
  const int*   dst   = (const int*)d_in[7];
  const int E = in_sizes[6];                     // 8192
  const int N = in_sizes[1] / CHW;               // 1024
  float* out = (float*)d_out;

  char* ws = (char*)d_ws;
  size_t off = 0;
  auto alloc = [&](size_t bytes) {
    void* p = ws + off;
    off = (off + bytes + 255) & ~(size_t)255;
    return p;
  };
  bf16* h     = (bf16*)alloc((size_t)E * C_DIM * sizeof(bf16));
  bf16* W2t   = (bf16*)alloc((size_t)N_DIM * K_DIM * sizeof(bf16));
  bf16* Eout  = (bf16*)alloc((size_t)E * N_DIM * sizeof(bf16));
  int* offs   = (int*)alloc((size_t)(N + 1) * sizeof(int));
  int2* pairs = (int2*)alloc((size_t)E * sizeof(int2));

  // CSR build (single block, LDS histogram + scan + cursor)
  build_csr<<<1, 1024, 0, stream>>>(dst, src, offs, pairs, E, N);

  // MLP layer 1 + weight transpose
  pose_mlp1<<<(E * C_DIM) / 256, 256, 0, stream>>>(pose, W1, b1, h);
  transpose_w2<<<dim3(N_DIM / 32, K_DIM / 32), dim3(32, 8), 0, stream>>>(W2, W2t);

  // MLP layer 2 (bf16 MFMA) + sigmoid
  gemm_sigmoid<<<dim3(E / 128, N_DIM / 128), 256, 0, stream>>>(h, W2t, b2, Eout);

  // FiLM + segment mean
  scatter_mean<<<dim3(N, 10), 256, 0, stream>>>((const ushort*)Eout, image, pairs, offs, out);
}

// Round 3
// 240.107 us; speedup vs baseline: 1.1246x; 1.0148x over previous
//
#include <hip/hip_runtime.h>

#define C_DIM 1280
#define K_DIM 1280      // GEMM K = C
#define N_DIM 2560      // GEMM N = 2C
#define HWSZ 16
#define CHW (C_DIM*HWSZ)

#define BM 256
#define BN 256
#define BK 64
#define NT (K_DIM / BK)   // 20 K-tiles

typedef __bf16 bf16;
typedef __attribute__((ext_vector_type(8))) __bf16 bf16x8;
typedef __attribute__((ext_vector_type(4))) float f32x4;

__device__ __forceinline__ void gload_lds16(const void* g, void* l) {
  __builtin_amdgcn_global_load_lds(
      (const __attribute__((address_space(1))) void*)g,
      (__attribute__((address_space(3))) void*)l, 16, 0, 0);
}

// ---------------- h = relu(pose @ W1 + b1), store bf16 ----------------
__global__ __launch_bounds__(256) void pose_mlp1(
    const float* __restrict__ pose, const float* __restrict__ W1,
    const float* __restrict__ b1, bf16* __restrict__ h)
{
  int idx = blockIdx.x * 256 + threadIdx.x;   // E*C threads, exact
  int e = idx / C_DIM;
  int c = idx - e * C_DIM;
  const float* p = pose + e * 9;
  float s = b1[c];
  #pragma unroll
  for (int k = 0; k < 9; k++) s += p[k] * W1[k * C_DIM + c];
  s = s > 0.f ? s : 0.f;
  h[idx] = (bf16)s;
}

// ---------------- W2 (1280 x 2560) -> W2t (2560 x 1280) bf16 ----------------
__global__ __launch_bounds__(256) void transpose_w2(
    const float* __restrict__ W2, bf16* __restrict__ W2t)
{
  __shared__ float tile[32][33];
  int n0 = blockIdx.x * 32;    // 2560/32 = 80
  int k0 = blockIdx.y * 32;    // 1280/32 = 40
  int tx = threadIdx.x;        // 32
  int ty = threadIdx.y;        // 8
  #pragma unroll
  for (int i = 0; i < 32; i += 8)
    tile[ty + i][tx] = W2[(size_t)(k0 + ty + i) * N_DIM + n0 + tx];
  __syncthreads();
  #pragma unroll
  for (int i = 0; i < 32; i += 8)
    W2t[(size_t)(n0 + ty + i) * K_DIM + k0 + tx] = (bf16)tile[tx][ty + i];
}

// ---------------- CSR build: one block, LDS counts/scan/cursor ----------------
__global__ __launch_bounds__(1024) void build_csr(
    const int* __restrict__ dst, const int* __restrict__ src,
    int* __restrict__ offsets, int2* __restrict__ pairs, int E, int N)
{
  __shared__ int buf[1024];
  __shared__ int cur[1024];
  const int t = threadIdx.x;
  buf[t] = 0;
  __syncthreads();
  for (int e = t; e < E; e += 1024) atomicAdd(&buf[dst[e]], 1);
  __syncthreads();
  const int v = buf[t];
  #pragma unroll
  for (int off = 1; off < 1024; off <<= 1) {
    int x = (t >= off) ? buf[t - off] : 0;
    __syncthreads();
    buf[t] += x;
    __syncthreads();
  }
  const int excl = buf[t] - v;
  cur[t] = excl;
  if (t < N) offsets[t] = excl;
  if (t == 0) offsets[N] = E;
  __syncthreads();
  for (int e = t; e < E; e += 1024) {
    const int d = dst[e];
    const int p = atomicAdd(&cur[d], 1);
    pairs[p] = make_int2(e, src[e]);
  }
}

// ---------------- GEMM 256x256 tile, 8 waves, dbuf LDS, counted vmcnt ----------------
// A: E x 1280 bf16 (row-major); Bt: 2560 x 1280 bf16 (N x K). Eo = sigmoid(A@Bt^T + b2), bf16.
__global__ __launch_bounds__(512, 2) void gemm_sigmoid(
    const bf16* __restrict__ A, const bf16* __restrict__ Bt,
    const float* __restrict__ b2, bf16* __restrict__ Eo)
{
  __shared__ __align__(16) char ldsA[2][BM * BK * 2];   // 2 x 32KB
  __shared__ __align__(16) char ldsB[2][BN * BK * 2];   // 2 x 32KB

  const int tid  = threadIdx.x;
  const int lane = tid & 63;
  const int wid  = tid >> 6;        // 8 waves: 2 (M) x 4 (N)
  const int wr   = wid >> 2;        // 0..1  -> 128-row half
  const int wc   = wid & 3;         // 0..3  -> 64-col quarter
  const int fr   = lane & 15;
  const int q    = lane >> 4;       // 0..3
  const int sw   = fr & 7;          // read-swizzle XOR (== row&7 for all our rows)
  const int g0   = ((q ^ sw) << 4);         // byte offset of kk=0 granule
  const int g1   = (((4 + q) ^ sw) << 4);   // kk=32 granule

  // XCD-aware swizzle (nwg = 320, divisible by 8)
  const int nwg  = gridDim.x;
  const int cpx  = nwg >> 3;
  const int swzb = (blockIdx.x & 7) * cpx + (blockIdx.x >> 3);
  const int mb   = swzb / (N_DIM / BN);
  const int nb   = swzb % (N_DIM / BN);
  const long bm  = (long)mb * BM;
  const long bn  = (long)nb * BN;

  f32x4 acc[8][4];
  #pragma unroll
  for (int m = 0; m < 8; m++)
    #pragma unroll
    for (int n = 0; n < 4; n++) acc[m][n] = f32x4{0.f, 0.f, 0.f, 0.f};

  // stage tile t into buffer c: linear LDS dest, inverse-swizzled global src
  auto STAGE = [&](int t, int c) {
    const int k0 = t * BK;
    #pragma unroll
    for (int i = 0; i < 4; ++i) {
      const int G   = i * 512 + tid;        // granule id 0..2047
      const int row = G >> 3;
      const int g   = G & 7;
      const int kg  = (g ^ (row & 7)) << 3; // element offset in K-tile
      char* dA = ldsA[c] + (size_t)(i * 512 + (wid << 6)) * 16;
      char* dB = ldsB[c] + (size_t)(i * 512 + (wid << 6)) * 16;
      gload_lds16(A  + (size_t)(bm + row) * K_DIM + k0 + kg, dA);
      gload_lds16(Bt + (size_t)(bn + row) * K_DIM + k0 + kg, dB);
    }
  };

  // prologue: tiles 0,1 in flight (16 loads/thread)
  STAGE(0, 0);
  STAGE(1, 1);

  for (int t = 0; t < NT; ++t) {
    const int c = t & 1;
    if (t < NT - 1) asm volatile("s_waitcnt vmcnt(8)" ::: "memory");
    else            asm volatile("s_waitcnt vmcnt(0)" ::: "memory");
    __builtin_amdgcn_s_barrier();
    __builtin_amdgcn_sched_barrier(0);

    const char* Ab = ldsA[c];
    const char* Bb = ldsB[c];

    bf16x8 bfr[4][2];
    #pragma unroll
    for (int n = 0; n < 4; ++n) {
      const int rb = (wc * 64 + n * 16 + fr) << 7;
      bfr[n][0] = *(const bf16x8*)(Bb + rb + g0);
      bfr[n][1] = *(const bf16x8*)(Bb + rb + g1);
    }
    __builtin_amdgcn_s_setprio(1);
    #pragma unroll
    for (int m = 0; m < 8; ++m) {
      const int ra = (wr * 128 + m * 16 + fr) << 7;
      bf16x8 a0 = *(const bf16x8*)(Ab + ra + g0);
      bf16x8 a1 = *(const bf16x8*)(Ab + ra + g1);
      #pragma unroll
      for (int n = 0; n < 4; ++n) {
        acc[m][n] = __builtin_amdgcn_mfma_f32_16x16x32_bf16(a0, bfr[n][0], acc[m][n], 0, 0, 0);
        acc[m][n] = __builtin_amdgcn_mfma_f32_16x16x32_bf16(a1, bfr[n][1], acc[m][n], 0, 0, 0);
      }
    }
    __builtin_amdgcn_s_setprio(0);

    asm volatile("" ::: "memory");
    __builtin_amdgcn_s_barrier();        // all waves' reads of buf c retired
    __builtin_amdgcn_sched_barrier(0);
    if (t < NT - 2) STAGE(t + 2, c);     // overwrite buf c for tile t+2
  }

  // epilogue: sigmoid(acc + b2) -> bf16
  #pragma unroll
  for (int m = 0; m < 8; ++m) {
    const long rowb = bm + wr * 128 + m * 16 + q * 4;
    #pragma unroll
    for (int n = 0; n < 4; ++n) {
      const long col = bn + wc * 64 + n * 16 + fr;
      const float bias = b2[col];
      #pragma unroll
      for (int r = 0; r < 4; ++r) {
        float v = acc[m][n][r] + bias;
        Eo[(rowb + r) * N_DIM + col] = (bf16)(1.f / (1.f + __expf(-v)));
      }
    }
  }
}

// ---------------- scatter-mean: out[n] = mean_e(gamma*image[src]+beta) ----------------
__global__ __launch_bounds__(256) void scatter_mean(
    const ushort* __restrict__ Eo,    // E x 2560 bf16, (gamma,beta) interleaved
    const float* __restrict__ image,  // N x C x 16
    const int2* __restrict__ pairs,   // (eid, src) in CSR order
    const int* __restrict__ offsets,  // N+1
    float* __restrict__ out)          // N x C x 16
{
  const int n = blockIdx.x;
  const int c0 = blockIdx.y * 128;
  const int t = threadIdx.x;
  const int q = t & 3;
  const int cl = t >> 2;
  const int ca = c0 + cl;
  const int cb = ca + 64;

  const int beg = offsets[n], end = offsets[n + 1];
  f32x4 acc0 = {0.f, 0.f, 0.f, 0.f};
  f32x4 acc1 = {0.f, 0.f, 0.f, 0.f};

  int2 pr;
  if (beg < end) pr = pairs[beg];
  for (int ei = beg; ei < end; ++ei) {
    const int2 cp = pr;
    if (ei + 1 < end) pr = pairs[ei + 1];
    const float* imgb = image + (size_t)cp.y * CHW;
    const ushort* gbp = Eo + (size_t)cp.x * N_DIM;
    const uint u0 = *(const uint*)(gbp + 2 * ca);   // lo=gamma, hi=beta
    const uint u1 = *(const uint*)(gbp + 2 * cb);
    const f32x4 i0 = *(const f32x4*)(imgb + ca * HWSZ + q * 4);
    const f32x4 i1 = *(const f32x4*)(imgb + cb * HWSZ + q * 4);
    const float g0 = __uint_as_float(u0 << 16);
    const float be0 = __uint_as_float(u0 & 0xffff0000u);
    const float g1 = __uint_as_float(u1 << 16);
    const float be1 = __uint_as_float(u1 & 0xffff0000u);
    acc0 += g0 * i0 + be0;
    acc1 += g1 * i1 + be1;
  }
  const int cnt = end - beg;
  const float inv = cnt > 0 ? 1.f / (float)cnt : 0.f;
  float* ob = out + (size_t)n * CHW;
  __builtin_nontemporal_store(acc0 * inv, (f32x4*)(ob + ca * HWSZ + q * 4));
  __builtin_nontemporal_store(acc1 * inv, (f32x4*)(ob + cb * HWSZ + q * 4));
}

// ---------------- launch ----------------
extern "C" void kernel_launch(void* const* d_in, const int* in_sizes, int n_in,
                              void* d_out, int out_size, void* d_ws, size_t ws_size,
                              hipStream_t stream) {
  const float* pose  = (const float*)d_in[0];
  const float* image = (const float*)d_in[1];
  const float* W1    = (const float*)d_in[2];
  const float* b1    = (const float*)d_in[3];
  const float* W2    = (const float*)d_in[4];
  const float* b2    = (const float*)d_in[5];
  const int*   src   = (const int*)d_in[6];
  const int*   dst   = (const int*)d_in[7];
  const int E = in_sizes[6];                     // 8192
  const int N = in_sizes[1] / CHW;               // 1024
  float* out = (float*)d_out;

  char* ws = (char*)d_ws;
  size_t off = 0;
  auto alloc = [&](size_t bytes) {
    void* p = ws + off;
    off = (off + bytes + 255) & ~(size_t)255;
    return p;
  };
  bf16* h     = (bf16*)alloc((size_t)E * C_DIM * sizeof(bf16));
  bf16* W2t   = (bf16*)alloc((size_t)N_DIM * K_DIM * sizeof(bf16));
  bf16* Eout  = (bf16*)alloc((size_t)E * N_DIM * sizeof(bf16));
  int* offs   = (int*)alloc((size_t)(N + 1) * sizeof(int));
  int2* pairs = (int2*)alloc((size_t)E * sizeof(int2));

  // CSR build (single block, LDS histogram + scan + cursor)
  build_csr<<<1, 1024, 0, stream>>>(dst, src, offs, pairs, E, N);

  // MLP layer 1 + weight transpose
  pose_mlp1<<<(E * C_DIM) / 256, 256, 0, stream>>>(pose, W1, b1, h);
  transpose_w2<<<dim3(N_DIM / 32, K_DIM / 32), dim3(32, 8), 0, stream>>>(W2, W2t);

  // MLP layer 2 (bf16 MFMA, 256^2 tile, counted-vmcnt pipeline) + sigmoid
  gemm_sigmoid<<<(E / BM) * (N_DIM / BN), 512, 0, stream>>>(h, W2t, b2, Eout);

  // FiLM + segment mean
  scatter_mean<<<dim3(N, 10), 256, 0, stream>>>((const ushort*)Eout, image, pairs, offs, out);
}

// Round 4
// 222.617 us; speedup vs baseline: 1.2129x; 1.0786x over previous
//
#include <hip/hip_runtime.h>

#define C_DIM 1280
#define K_DIM 1280      // GEMM K = C
#define N_DIM 2560      // GEMM N = 2C
#define HWSZ 16
#define CHW (C_DIM*HWSZ)

#define BM 256
#define BN 320
#define BK 64
#define NT (K_DIM / BK)   // 20 K-tiles

typedef __bf16 bf16;
typedef __attribute__((ext_vector_type(8))) __bf16 bf16x8;
typedef __attribute__((ext_vector_type(4))) float f32x4;

template<int V> struct IC { static constexpr int v = V; };

__device__ __forceinline__ void gload_lds16(const void* g, void* l) {
  __builtin_amdgcn_global_load_lds(
      (const __attribute__((address_space(1))) void*)g,
      (__attribute__((address_space(3))) void*)l, 16, 0, 0);
}

// ---------------- h = relu(pose @ W1 + b1), store bf16 ----------------
__global__ __launch_bounds__(256) void pose_mlp1(
    const float* __restrict__ pose, const float* __restrict__ W1,
    const float* __restrict__ b1, bf16* __restrict__ h)
{
  int idx = blockIdx.x * 256 + threadIdx.x;   // E*C threads, exact
  int e = idx / C_DIM;
  int c = idx - e * C_DIM;
  const float* p = pose + e * 9;
  float s = b1[c];
  #pragma unroll
  for (int k = 0; k < 9; k++) s += p[k] * W1[k * C_DIM + c];
  s = s > 0.f ? s : 0.f;
  h[idx] = (bf16)s;
}

// ---------------- W2 (1280 x 2560) -> W2t (2560 x 1280) bf16 ----------------
__global__ __launch_bounds__(256) void transpose_w2(
    const float* __restrict__ W2, bf16* __restrict__ W2t)
{
  __shared__ float tile[32][33];
  int n0 = blockIdx.x * 32;    // 2560/32 = 80
  int k0 = blockIdx.y * 32;    // 1280/32 = 40
  int tx = threadIdx.x;        // 32
  int ty = threadIdx.y;        // 8
  #pragma unroll
  for (int i = 0; i < 32; i += 8)
    tile[ty + i][tx] = W2[(size_t)(k0 + ty + i) * N_DIM + n0 + tx];
  __syncthreads();
  #pragma unroll
  for (int i = 0; i < 32; i += 8)
    W2t[(size_t)(n0 + ty + i) * K_DIM + k0 + tx] = (bf16)tile[tx][ty + i];
}

// ---------------- CSR build: one block, LDS counts/scan/cursor ----------------
__global__ __launch_bounds__(1024) void build_csr(
    const int* __restrict__ dst, const int* __restrict__ src,
    int* __restrict__ offsets, int2* __restrict__ pairs, int E, int N)
{
  __shared__ int buf[1024];
  __shared__ int cur[1024];
  const int t = threadIdx.x;
  buf[t] = 0;
  __syncthreads();
  for (int e = t; e < E; e += 1024) atomicAdd(&buf[dst[e]], 1);
  __syncthreads();
  const int v = buf[t];
  #pragma unroll
  for (int off = 1; off < 1024; off <<= 1) {
    int x = (t >= off) ? buf[t - off] : 0;
    __syncthreads();
    buf[t] += x;
    __syncthreads();
  }
  const int excl = buf[t] - v;
  cur[t] = excl;
  if (t < N) offsets[t] = excl;
  if (t == 0) offsets[N] = E;
  __syncthreads();
  for (int e = t; e < E; e += 1024) {
    const int d = dst[e];
    const int p = atomicAdd(&cur[d], 1);
    pairs[p] = make_int2(e, src[e]);
  }
}

// ---------------- GEMM 256x320 tile, 8 waves, 4-phase/K-tile counted-vmcnt pipeline ----
// A: E x 1280 bf16 (row-major); Bt: 2560 x 1280 bf16 (N x K). Eo = sigmoid(A@Bt^T + b2), bf16.
__global__ __launch_bounds__(512, 2) void gemm_sigmoid(
    const bf16* __restrict__ A, const bf16* __restrict__ Bt,
    const float* __restrict__ b2, bf16* __restrict__ Eo)
{
  __shared__ __align__(16) char ldsA[2][BM * BK * 2];   // 2 x 32KB
  __shared__ __align__(16) char ldsB[2][BN * BK * 2];   // 2 x 40KB

  const int tid  = threadIdx.x;
  const int lane = tid & 63;
  const int wid  = tid >> 6;        // 8 waves: 2 (M) x 4 (N)
  const int wr   = wid >> 2;        // 0..1  -> 128-row half
  const int wc   = wid & 3;         // 0..3  -> 80-col slice
  const int fr   = lane & 15;
  const int q    = lane >> 4;       // 0..3
  const int sw   = fr & 7;          // read-swizzle XOR (== row&7 for all frag rows)
  const int g0   = ((q ^ sw) << 4);         // byte offset of kk=0 granule
  const int g1   = (((4 + q) ^ sw) << 4);   // kk=32 granule

  // XCD-aware swizzle (nwg = 256, divisible by 8)
  const int swzb = (blockIdx.x & 7) * 32 + (blockIdx.x >> 3);
  const int mb   = swzb >> 3;       // 0..31
  const int nb   = swzb & 7;        // 0..7
  const long bm  = (long)mb * BM;
  const long bn  = (long)nb * BN;

  const bf16* Agl = A  + bm * K_DIM;
  const bf16* Bgl = Bt + bn * K_DIM;

  f32x4 acc[8][5];
  #pragma unroll
  for (int m = 0; m < 8; m++)
    #pragma unroll
    for (int n = 0; n < 5; n++) acc[m][n] = f32x4{0.f, 0.f, 0.f, 0.f};

  // --- staging: linear LDS dest, inverse-swizzled global src; 1 gload_lds per call ---
  // A chunk p (p=0..3): rows [32p,32p+32) U [128+32p, 128+32p+32)  (= phase p's rows)
  auto STAGE_A = [&](int tt, int b, int p) {
    const int wb = (wid < 4) ? (p * 256 + wid * 64) : (1024 + p * 256 + (wid - 4) * 64);
    const int G  = wb + lane;
    const int row = G >> 3, g = G & 7;
    const int kg = (g ^ (row & 7)) << 3;
    gload_lds16(Agl + (size_t)row * K_DIM + tt * BK + kg, ldsA[b] + (size_t)wb * 16);
  };
  // B chunk i (i=0..4): rows [64i, 64i+64)
  auto STAGE_B = [&](int tt, int b, int i) {
    const int wb = i * 512 + wid * 64;
    const int G  = wb + lane;
    const int row = G >> 3, g = G & 7;
    const int kg = (g ^ (row & 7)) << 3;
    gload_lds16(Bgl + (size_t)row * K_DIM + tt * BK + kg, ldsB[b] + (size_t)wb * 16);
  };

  // prologue: stage tile 0 (order: B0..B4, A0..A3 — vmcnt math depends on this)
  STAGE_B(0, 0, 0); STAGE_B(0, 0, 1); STAGE_B(0, 0, 2);
  STAGE_B(0, 0, 3); STAGE_B(0, 0, 4);
  STAGE_A(0, 0, 0); STAGE_A(0, 0, 1); STAGE_A(0, 0, 2); STAGE_A(0, 0, 3);
  asm volatile("s_waitcnt vmcnt(3)" ::: "memory");   // B + A0 landed
  __builtin_amdgcn_sched_barrier(0);
  __builtin_amdgcn_s_barrier();
  __builtin_amdgcn_sched_barrier(0);

  auto tile_body = [&](auto PFc, int t) {
    constexpr bool PF = (bool)decltype(PFc)::v;
    const int c  = t & 1;
    const int cn = (t + 1) & 1;
    const int tn = t + 1;
    const char* Ab = ldsA[c];
    const char* Bb = ldsB[c];

    bf16x8 bfr[5][2];

    auto do_phase = [&](auto Pc) {
      constexpr int p = decltype(Pc)::v;
      bf16x8 a[2][2];
      #pragma unroll
      for (int mm = 0; mm < 2; ++mm) {
        const int ra = (wr * 128 + (2 * p + mm) * 16 + fr) << 7;
        a[mm][0] = *(const bf16x8*)(Ab + ra + g0);
        a[mm][1] = *(const bf16x8*)(Ab + ra + g1);
      }
      __builtin_amdgcn_sched_barrier(0);
      __builtin_amdgcn_s_barrier();
      asm volatile("s_waitcnt lgkmcnt(0)" ::: "memory");
      __builtin_amdgcn_sched_barrier(0);
      __builtin_amdgcn_s_setprio(1);
      #pragma unroll
      for (int mm = 0; mm < 2; ++mm)
        #pragma unroll
        for (int n = 0; n < 5; ++n) {
          acc[2*p+mm][n] = __builtin_amdgcn_mfma_f32_16x16x32_bf16(a[mm][0], bfr[n][0], acc[2*p+mm][n], 0, 0, 0);
          acc[2*p+mm][n] = __builtin_amdgcn_mfma_f32_16x16x32_bf16(a[mm][1], bfr[n][1], acc[2*p+mm][n], 0, 0, 0);
        }
      __builtin_amdgcn_s_setprio(0);
      __builtin_amdgcn_sched_barrier(0);
    };
    auto post_barrier = [&]() {
      __builtin_amdgcn_sched_barrier(0);
      __builtin_amdgcn_s_barrier();
      __builtin_amdgcn_sched_barrier(0);
    };

    // ---- phase 0: stage B0-B2(t+1); read B frags + A rows [32p..] p=0; MFMA m0,m1 ----
    if constexpr (PF) { STAGE_B(tn, cn, 0); STAGE_B(tn, cn, 1); STAGE_B(tn, cn, 2); }
    #pragma unroll
    for (int n = 0; n < 5; ++n) {
      const int rb = (wc * 80 + n * 16 + fr) << 7;
      bfr[n][0] = *(const bf16x8*)(Bb + rb + g0);
      bfr[n][1] = *(const bf16x8*)(Bb + rb + g1);
    }
    do_phase(IC<0>{});
    if constexpr (PF) asm volatile("s_waitcnt vmcnt(5)" ::: "memory");  // A1(t) landed
    else              asm volatile("s_waitcnt vmcnt(2)" ::: "memory");
    post_barrier();

    // ---- phase 1: stage B3,B4,A0(t+1); MFMA m2,m3 ----
    if constexpr (PF) { STAGE_B(tn, cn, 3); STAGE_B(tn, cn, 4); STAGE_A(tn, cn, 0); }
    do_phase(IC<1>{});
    if constexpr (PF) asm volatile("s_waitcnt vmcnt(7)" ::: "memory");  // A2(t) landed
    else              asm volatile("s_waitcnt vmcnt(1)" ::: "memory");
    post_barrier();

    // ---- phase 2: stage A1(t+1); MFMA m4,m5 ----
    if constexpr (PF) { STAGE_A(tn, cn, 1); }
    do_phase(IC<2>{});
    if constexpr (PF) asm volatile("s_waitcnt vmcnt(7)" ::: "memory");  // A3(t) landed
    else              asm volatile("s_waitcnt vmcnt(0)" ::: "memory");
    post_barrier();

    // ---- phase 3: stage A2,A3(t+1); MFMA m6,m7 ----
    if constexpr (PF) { STAGE_A(tn, cn, 2); STAGE_A(tn, cn, 3); }
    do_phase(IC<3>{});
    if constexpr (PF) asm volatile("s_waitcnt vmcnt(3)" ::: "memory");  // B(t+1)+A0(t+1) landed
    post_barrier();
  };

  for (int t = 0; t < NT - 1; ++t) tile_body(IC<1>{}, t);
  tile_body(IC<0>{}, NT - 1);

  // epilogue: sigmoid(acc + b2) -> bf16
  #pragma unroll
  for (int m = 0; m < 8; ++m) {
    const long rowb = bm + wr * 128 + m * 16 + q * 4;
    #pragma unroll
    for (int n = 0; n < 5; ++n) {
      const long col = bn + wc * 80 + n * 16 + fr;
      const float bias = b2[col];
      #pragma unroll
      for (int r = 0; r < 4; ++r) {
        float v = acc[m][n][r] + bias;
        Eo[(rowb + r) * N_DIM + col] = (bf16)(1.f / (1.f + __expf(-v)));
      }
    }
  }
}

// ---------------- scatter-mean: out[n] = mean_e(gamma*image[src]+beta) ----------------
__global__ __launch_bounds__(256) void scatter_mean(
    const ushort* __restrict__ Eo,    // E x 2560 bf16, (gamma,beta) interleaved
    const float* __restrict__ image,  // N x C x 16
    const int2* __restrict__ pairs,   // (eid, src) in CSR order
    const int* __restrict__ offsets,  // N+1
    float* __restrict__ out)          // N x C x 16
{
  const int n = blockIdx.x;
  const int c0 = blockIdx.y * 128;
  const int t = threadIdx.x;
  const int q = t & 3;
  const int cl = t >> 2;
  const int ca = c0 + cl;
  const int cb = ca + 64;

  const int beg = offsets[n], end = offsets[n + 1];
  f32x4 acc0 = {0.f, 0.f, 0.f, 0.f};
  f32x4 acc1 = {0.f, 0.f, 0.f, 0.f};

  int2 pr;
  if (beg < end) pr = pairs[beg];
  for (int ei = beg; ei < end; ++ei) {
    const int2 cp = pr;
    if (ei + 1 < end) pr = pairs[ei + 1];
    const float* imgb = image + (size_t)cp.y * CHW;
    const ushort* gbp = Eo + (size_t)cp.x * N_DIM;
    const uint u0 = *(const uint*)(gbp + 2 * ca);   // lo=gamma, hi=beta
    const uint u1 = *(const uint*)(gbp + 2 * cb);
    const f32x4 i0 = *(const f32x4*)(imgb + ca * HWSZ + q * 4);
    const f32x4 i1 = *(const f32x4*)(imgb + cb * HWSZ + q * 4);
    const float g0 = __uint_as_float(u0 << 16);
    const float be0 = __uint_as_float(u0 & 0xffff0000u);
    const float g1 = __uint_as_float(u1 << 16);
    const float be1 = __uint_as_float(u1 & 0xffff0000u);
    acc0 += g0 * i0 + be0;
    acc1 += g1 * i1 + be1;
  }
  const int cnt = end - beg;
  const float inv = cnt > 0 ? 1.f / (float)cnt : 0.f;
  float* ob = out + (size_t)n * CHW;
  __builtin_nontemporal_store(acc0 * inv, (f32x4*)(ob + ca * HWSZ + q * 4));
  __builtin_nontemporal_store(acc1 * inv, (f32x4*)(ob + cb * HWSZ + q * 4));
}

// ---------------- launch ----------------
extern "C" void kernel_launch(void* const* d_in, const int* in_sizes, int n_in,
                              void* d_out, int out_size, void* d_ws, size_t ws_size,
                              hipStream_t stream) {
  const float* pose  = (const float*)d_in[0];
  const float* image = (const float*)d_in[1];
  const float* W1    = (const float*)d_in[2];
  const float* b1    = (const float*)d_in[3];
  const float* W2    = (const float*)d_in[4];
  const float* b2    = (const float*)d_in[5];
  const int*   src   = (const int*)d_in[6];
  const int*   dst   = (const int*)d_in[7];
  const int E = in_sizes[6];                     // 8192
  const int N = in_sizes[1] / CHW;               // 1024
  float* out = (float*)d_out;

  char* ws = (char*)d_ws;
  size_t off = 0;
  auto alloc = [&](size_t bytes) {
    void* p = ws + off;
    off = (off + bytes + 255) & ~(size_t)255;
    return p;
  };
  bf16* h     = (bf16*)alloc((size_t)E * C_DIM * sizeof(bf16));
  bf16* W2t   = (bf16*)alloc((size_t)N_DIM * K_DIM * sizeof(bf16));
  bf16* Eout  = (bf16*)alloc((size_t)E * N_DIM * sizeof(bf16));
  int* offs   = (int*)alloc((size_t)(N + 1) * sizeof(int));
  int2* pairs = (int2*)alloc((size_t)E * sizeof(int2));

  // CSR build (single block, LDS histogram + scan + cursor)
  build_csr<<<1, 1024, 0, stream>>>(dst, src, offs, pairs, E, N);

  // MLP layer 1 + weight transpose
  pose_mlp1<<<(E * C_DIM) / 256, 256, 0, stream>>>(pose, W1, b1, h);
  transpose_w2<<<dim3(N_DIM / 32, K_DIM / 32), dim3(32, 8), 0, stream>>>(W2, W2t);

  // MLP layer 2 (bf16 MFMA, 256x320 tile, 4-phase counted-vmcnt pipeline) + sigmoid
  gemm_sigmoid<<<(E / BM) * (N_DIM / BN), 512, 0, stream>>>(h, W2t, b2, Eout);

  // FiLM + segment mean
  scatter_mean<<<dim3(N, 10), 256, 0, stream>>>((const ushort*)Eout, image, pairs, offs, out);
}

// Round 5
// 194.174 us; speedup vs baseline: 1.3906x; 1.1465x over previous
//
#include <hip/hip_runtime.h>

#define C_DIM 1280
#define K_DIM 1280      // GEMM K = C
#define N_DIM 2560      // GEMM N = 2C
#define HWSZ 16
#define CHW (C_DIM*HWSZ)

#define BM 256
#define BN 320
#define BK 64
#define NT (K_DIM / BK)   // 20 K-tiles

typedef __bf16 bf16;
typedef __attribute__((ext_vector_type(8))) __bf16 bf16x8;
typedef __attribute__((ext_vector_type(8))) unsigned short u16x8;
typedef __attribute__((ext_vector_type(4))) float f32x4;

template<int V> struct IC { static constexpr int v = V; };

__device__ __forceinline__ void gload_lds16(const void* g, void* l) {
  __builtin_amdgcn_global_load_lds(
      (const __attribute__((address_space(1))) void*)g,
      (__attribute__((address_space(3))) void*)l, 16, 0, 0);
}

// ---------------- image fp32 -> bf16 (RNE via compiler cvt) ----------------
__global__ __launch_bounds__(256) void convert_image(
    const float* __restrict__ in, bf16* __restrict__ outb)
{
  const size_t i = ((size_t)blockIdx.x * 256 + threadIdx.x) * 8;
  const f32x4 a = *(const f32x4*)(in + i);
  const f32x4 b = *(const f32x4*)(in + i + 4);
  bf16x8 o;
  o[0]=(bf16)a[0]; o[1]=(bf16)a[1]; o[2]=(bf16)a[2]; o[3]=(bf16)a[3];
  o[4]=(bf16)b[0]; o[5]=(bf16)b[1]; o[6]=(bf16)b[2]; o[7]=(bf16)b[3];
  *(bf16x8*)(outb + i) = o;
}

// ---------------- h = relu(pose @ W1 + b1), store bf16 ----------------
__global__ __launch_bounds__(256) void pose_mlp1(
    const float* __restrict__ pose, const float* __restrict__ W1,
    const float* __restrict__ b1, bf16* __restrict__ h)
{
  const int c = blockIdx.x * 256 + threadIdx.x;   // grid.x = C_DIM/256
  const int e = blockIdx.y;
  const float* p = pose + e * 9;
  float s = b1[c];
  #pragma unroll
  for (int k = 0; k < 9; k++) s += p[k] * W1[k * C_DIM + c];
  s = s > 0.f ? s : 0.f;
  h[(size_t)e * C_DIM + c] = (bf16)s;
}

// ---------------- W2 (1280 x 2560) -> W2t (2560 x 1280) bf16 ----------------
__global__ __launch_bounds__(256) void transpose_w2(
    const float* __restrict__ W2, bf16* __restrict__ W2t)
{
  __shared__ float tile[32][33];
  int n0 = blockIdx.x * 32;    // 2560/32 = 80
  int k0 = blockIdx.y * 32;    // 1280/32 = 40
  int tx = threadIdx.x;        // 32
  int ty = threadIdx.y;        // 8
  #pragma unroll
  for (int i = 0; i < 32; i += 8)
    tile[ty + i][tx] = W2[(size_t)(k0 + ty + i) * N_DIM + n0 + tx];
  __syncthreads();
  #pragma unroll
  for (int i = 0; i < 32; i += 8)
    W2t[(size_t)(n0 + ty + i) * K_DIM + k0 + tx] = (bf16)tile[tx][ty + i];
}

// ---------------- CSR build: one block, LDS counts/scan/cursor ----------------
__global__ __launch_bounds__(1024) void build_csr(
    const int* __restrict__ dst, const int* __restrict__ src,
    int* __restrict__ offsets, int2* __restrict__ pairs, int E, int N)
{
  __shared__ int buf[1024];
  __shared__ int cur[1024];
  const int t = threadIdx.x;
  buf[t] = 0;
  __syncthreads();
  for (int e = t; e < E; e += 1024) atomicAdd(&buf[dst[e]], 1);
  __syncthreads();
  const int v = buf[t];
  #pragma unroll
  for (int off = 1; off < 1024; off <<= 1) {
    int x = (t >= off) ? buf[t - off] : 0;
    __syncthreads();
    buf[t] += x;
    __syncthreads();
  }
  const int excl = buf[t] - v;
  cur[t] = excl;
  if (t < N) offsets[t] = excl;
  if (t == 0) offsets[N] = E;
  __syncthreads();
  for (int e = t; e < E; e += 1024) {
    const int d = dst[e];
    const int p = atomicAdd(&cur[d], 1);
    pairs[p] = make_int2(e, src[e]);
  }
}

// ---------------- GEMM 256x320 tile, 8 waves, 4-phase/K-tile counted-vmcnt pipeline ----
__global__ __launch_bounds__(512, 2) void gemm_sigmoid(
    const bf16* __restrict__ A, const bf16* __restrict__ Bt,
    const float* __restrict__ b2, bf16* __restrict__ Eo)
{
  __shared__ __align__(16) char ldsA[2][BM * BK * 2];   // 2 x 32KB
  __shared__ __align__(16) char ldsB[2][BN * BK * 2];   // 2 x 40KB

  const int tid  = threadIdx.x;
  const int lane = tid & 63;
  const int wid  = tid >> 6;        // 8 waves: 2 (M) x 4 (N)
  const int wr   = wid >> 2;        // 0..1  -> 128-row half
  const int wc   = wid & 3;         // 0..3  -> 80-col slice
  const int fr   = lane & 15;
  const int q    = lane >> 4;       // 0..3
  const int sw   = fr & 7;          // read-swizzle XOR (== row&7 for all frag rows)
  const int g0   = ((q ^ sw) << 4);         // byte offset of kk=0 granule
  const int g1   = (((4 + q) ^ sw) << 4);   // kk=32 granule

  // XCD-aware swizzle (nwg = 256, divisible by 8)
  const int swzb = (blockIdx.x & 7) * 32 + (blockIdx.x >> 3);
  const int mb   = swzb >> 3;       // 0..31
  const int nb   = swzb & 7;        // 0..7
  const long bm  = (long)mb * BM;
  const long bn  = (long)nb * BN;

  const bf16* Agl = A  + bm * K_DIM;
  const bf16* Bgl = Bt + bn * K_DIM;

  f32x4 acc[8][5];
  #pragma unroll
  for (int m = 0; m < 8; m++)
    #pragma unroll
    for (int n = 0; n < 5; n++) acc[m][n] = f32x4{0.f, 0.f, 0.f, 0.f};

  // A chunk p (p=0..3): rows [32p,32p+32) U [128+32p, 128+32p+32)
  auto STAGE_A = [&](int tt, int b, int p) {
    const int wb = (wid < 4) ? (p * 256 + wid * 64) : (1024 + p * 256 + (wid - 4) * 64);
    const int G  = wb + lane;
    const int row = G >> 3, g = G & 7;
    const int kg = (g ^ (row & 7)) << 3;
    gload_lds16(Agl + (size_t)row * K_DIM + tt * BK + kg, ldsA[b] + (size_t)wb * 16);
  };
  // B chunk i (i=0..4): rows [64i, 64i+64)
  auto STAGE_B = [&](int tt, int b, int i) {
    const int wb = i * 512 + wid * 64;
    const int G  = wb + lane;
    const int row = G >> 3, g = G & 7;
    const int kg = (g ^ (row & 7)) << 3;
    gload_lds16(Bgl + (size_t)row * K_DIM + tt * BK + kg, ldsB[b] + (size_t)wb * 16);
  };

  // prologue: stage tile 0 (order: B0..B4, A0..A3 — vmcnt math depends on this)
  STAGE_B(0, 0, 0); STAGE_B(0, 0, 1); STAGE_B(0, 0, 2);
  STAGE_B(0, 0, 3); STAGE_B(0, 0, 4);
  STAGE_A(0, 0, 0); STAGE_A(0, 0, 1); STAGE_A(0, 0, 2); STAGE_A(0, 0, 3);
  asm volatile("s_waitcnt vmcnt(3)" ::: "memory");   // B + A0 landed
  __builtin_amdgcn_sched_barrier(0);
  __builtin_amdgcn_s_barrier();
  __builtin_amdgcn_sched_barrier(0);

  auto tile_body = [&](auto PFc, int t) {
    constexpr bool PF = (bool)decltype(PFc)::v;
    const int c  = t & 1;
    const int cn = (t + 1) & 1;
    const int tn = t + 1;
    const char* Ab = ldsA[c];
    const char* Bb = ldsB[c];

    bf16x8 bfr[5][2];

    auto do_phase = [&](auto Pc) {
      constexpr int p = decltype(Pc)::v;
      bf16x8 a[2][2];
      #pragma unroll
      for (int mm = 0; mm < 2; ++mm) {
        const int ra = (wr * 128 + (2 * p + mm) * 16 + fr) << 7;
        a[mm][0] = *(const bf16x8*)(Ab + ra + g0);
        a[mm][1] = *(const bf16x8*)(Ab + ra + g1);
      }
      __builtin_amdgcn_sched_barrier(0);
      __builtin_amdgcn_s_barrier();
      asm volatile("s_waitcnt lgkmcnt(0)" ::: "memory");
      __builtin_amdgcn_sched_barrier(0);
      __builtin_amdgcn_s_setprio(1);
      #pragma unroll
      for (int mm = 0; mm < 2; ++mm)
        #pragma unroll
        for (int n = 0; n < 5; ++n) {
          acc[2*p+mm][n] = __builtin_amdgcn_mfma_f32_16x16x32_bf16(a[mm][0], bfr[n][0], acc[2*p+mm][n], 0, 0, 0);
          acc[2*p+mm][n] = __builtin_amdgcn_mfma_f32_16x16x32_bf16(a[mm][1], bfr[n][1], acc[2*p+mm][n], 0, 0, 0);
        }
      __builtin_amdgcn_s_setprio(0);
      __builtin_amdgcn_sched_barrier(0);
    };
    auto post_barrier = [&]() {
      __builtin_amdgcn_sched_barrier(0);
      __builtin_amdgcn_s_barrier();
      __builtin_amdgcn_sched_barrier(0);
    };

    // ---- phase 0 ----
    if constexpr (PF) { STAGE_B(tn, cn, 0); STAGE_B(tn, cn, 1); STAGE_B(tn, cn, 2); }
    #pragma unroll
    for (int n = 0; n < 5; ++n) {
      const int rb = (wc * 80 + n * 16 + fr) << 7;
      bfr[n][0] = *(const bf16x8*)(Bb + rb + g0);
      bfr[n][1] = *(const bf16x8*)(Bb + rb + g1);
    }
    do_phase(IC<0>{});
    if constexpr (PF) asm volatile("s_waitcnt vmcnt(5)" ::: "memory");  // A1(t) landed
    else              asm volatile("s_waitcnt vmcnt(2)" ::: "memory");
    post_barrier();

    // ---- phase 1 ----
    if constexpr (PF) { STAGE_B(tn, cn, 3); STAGE_B(tn, cn, 4); STAGE_A(tn, cn, 0); }
    do_phase(IC<1>{});
    if constexpr (PF) asm volatile("s_waitcnt vmcnt(7)" ::: "memory");  // A2(t) landed
    else              asm volatile("s_waitcnt vmcnt(1)" ::: "memory");
    post_barrier();

    // ---- phase 2 ----
    if constexpr (PF) { STAGE_A(tn, cn, 1); }
    do_phase(IC<2>{});
    if constexpr (PF) asm volatile("s_waitcnt vmcnt(7)" ::: "memory");  // A3(t) landed
    else              asm volatile("s_waitcnt vmcnt(0)" ::: "memory");
    post_barrier();

    // ---- phase 3 ----
    if constexpr (PF) { STAGE_A(tn, cn, 2); STAGE_A(tn, cn, 3); }
    do_phase(IC<3>{});
    if constexpr (PF) asm volatile("s_waitcnt vmcnt(3)" ::: "memory");  // B(t+1)+A0(t+1) landed
    post_barrier();
  };

  for (int t = 0; t < NT - 1; ++t) tile_body(IC<1>{}, t);
  tile_body(IC<0>{}, NT - 1);

  // epilogue: sigmoid(acc + b2) -> bf16
  #pragma unroll
  for (int m = 0; m < 8; ++m) {
    const long rowb = bm + wr * 128 + m * 16 + q * 4;
    #pragma unroll
    for (int n = 0; n < 5; ++n) {
      const long col = bn + wc * 80 + n * 16 + fr;
      const float bias = b2[col];
      #pragma unroll
      for (int r = 0; r < 4; ++r) {
        float v = acc[m][n][r] + bias;
        Eo[(rowb + r) * N_DIM + col] = (bf16)(1.f / (1.f + __expf(-v)));
      }
    }
  }
}

// ---------------- scatter-mean: out[n] = mean_e(gamma*image_bf16[src]+beta) ----------------
// grid (N, 10); block 256. 128 ch/block; q=t&1 hw-octet, cl=t>>1 channel.
__global__ __launch_bounds__(256) void scatter_mean(
    const ushort* __restrict__ Eo,      // E x 2560 bf16, (gamma,beta) interleaved
    const ushort* __restrict__ imgb16,  // N x C x 16 bf16 bits
    const int2* __restrict__ pairs,     // (eid, src) in CSR order
    const int* __restrict__ offsets,    // N+1
    float* __restrict__ out)            // N x C x 16 fp32
{
  const int n = blockIdx.x;
  const int c0 = blockIdx.y * 128;
  const int t = threadIdx.x;
  const int q = t & 1;
  const int cl = t >> 1;
  const int ca = c0 + cl;
  const int ioff = ca * HWSZ + q * 8;   // element offset into image/out row

  const int beg = offsets[n], end = offsets[n + 1];
  f32x4 aA0{0.f,0.f,0.f,0.f}, aA1{0.f,0.f,0.f,0.f};
  f32x4 aB0{0.f,0.f,0.f,0.f}, aB1{0.f,0.f,0.f,0.f};

  int2 p0{0,0}, p1{0,0};
  if (beg < end) p0 = pairs[beg];
  if (beg + 1 < end) p1 = pairs[beg + 1];

  auto edge = [&](int2 cp, f32x4& x0, f32x4& x1) {
    const u16x8 iv = *(const u16x8*)(imgb16 + (size_t)cp.y * CHW + ioff);
    const uint u = *(const uint*)(Eo + (size_t)cp.x * N_DIM + 2 * ca);
    const float g  = __uint_as_float(u << 16);
    const float be = __uint_as_float(u & 0xffff0000u);
    f32x4 i0, i1;
    i0[0] = __uint_as_float((uint)iv[0] << 16);
    i0[1] = __uint_as_float((uint)iv[1] << 16);
    i0[2] = __uint_as_float((uint)iv[2] << 16);
    i0[3] = __uint_as_float((uint)iv[3] << 16);
    i1[0] = __uint_as_float((uint)iv[4] << 16);
    i1[1] = __uint_as_float((uint)iv[5] << 16);
    i1[2] = __uint_as_float((uint)iv[6] << 16);
    i1[3] = __uint_as_float((uint)iv[7] << 16);
    x0 += g * i0 + be;
    x1 += g * i1 + be;
  };

  int ei = beg;
  for (; ei + 1 < end; ei += 2) {
    const int2 c0p = p0, c1p = p1;
    if (ei + 2 < end) p0 = pairs[ei + 2];
    if (ei + 3 < end) p1 = pairs[ei + 3];
    edge(c0p, aA0, aA1);
    edge(c1p, aB0, aB1);
  }
  if (ei < end) edge(p0, aA0, aA1);

  const int cnt = end - beg;
  const float inv = cnt > 0 ? 1.f / (float)cnt : 0.f;
  const f32x4 r0 = (aA0 + aB0) * inv;
  const f32x4 r1 = (aA1 + aB1) * inv;
  float* ob = out + (size_t)n * CHW + ioff;
  __builtin_nontemporal_store(r0, (f32x4*)ob);
  __builtin_nontemporal_store(r1, (f32x4*)(ob + 4));
}

// ---------------- launch ----------------
extern "C" void kernel_launch(void* const* d_in, const int* in_sizes, int n_in,
                              void* d_out, int out_size, void* d_ws, size_t ws_size,
                              hipStream_t stream) {
  const float* pose  = (const float*)d_in[0];
  const float* image = (const float*)d_in[1];
  const float* W1    = (const float*)d_in[2];
  const float* b1    = (const float*)d_in[3];
  const float* W2    = (const float*)d_in[4];
  const float* b2    = (const float*)d_in[5];
  const int*   src   = (const int*)d_in[6];
  const int*   dst   = (const int*)d_in[7];
  const int E = in_sizes[6];                     // 8192
  const int N = in_sizes[1] / CHW;               // 1024
  float* out = (float*)d_out;

  char* ws = (char*)d_ws;
  size_t off = 0;
  auto alloc = [&](size_t bytes) {
    void* p = ws + off;
    off = (off + bytes + 255) & ~(size_t)255;
    return p;
  };
  bf16* h     = (bf16*)alloc((size_t)E * C_DIM * sizeof(bf16));
  bf16* W2t   = (bf16*)alloc((size_t)N_DIM * K_DIM * sizeof(bf16));
  bf16* Eout  = (bf16*)alloc((size_t)E * N_DIM * sizeof(bf16));
  bf16* imgb  = (bf16*)alloc((size_t)N * CHW * sizeof(bf16));
  int* offs   = (int*)alloc((size_t)(N + 1) * sizeof(int));
  int2* pairs = (int2*)alloc((size_t)E * sizeof(int2));

  // image fp32 -> bf16 (N*CHW/2048 blocks, exact)
  convert_image<<<(N * CHW) / 2048, 256, 0, stream>>>(image, imgb);

  // CSR build (single block, LDS histogram + scan + cursor)
  build_csr<<<1, 1024, 0, stream>>>(dst, src, offs, pairs, E, N);

  // MLP layer 1 + weight transpose
  pose_mlp1<<<dim3(C_DIM / 256, E), 256, 0, stream>>>(pose, W1, b1, h);
  transpose_w2<<<dim3(N_DIM / 32, K_DIM / 32), dim3(32, 8), 0, stream>>>(W2, W2t);

  // MLP layer 2 (bf16 MFMA, 256x320 tile, 4-phase counted-vmcnt pipeline) + sigmoid
  gemm_sigmoid<<<(E / BM) * (N_DIM / BN), 512, 0, stream>>>(h, W2t, b2, Eout);

  // FiLM + segment mean (bf16 image)
  scatter_mean<<<dim3(N, 10), 256, 0, stream>>>(
      (const ushort*)Eout, (const ushort*)imgb, pairs, offs, out);
}